// Round 3
// baseline (602.182 us; speedup 1.0000x reference)
//
#include <hip/hip_runtime.h>

#define NN 50000
#define NE 1600000
#define D 64
#define NR 6
#define NSEG (NN * NR)          // 300000
#define SB 512
#define SNB ((NSEG + SB - 1) / SB)   // 586
#define CH 16                   // nodes per wave in mix_k; 50000 = 16*3125 exactly

__global__ void zero_i32_k(int* __restrict__ p, int n) {
    int i = blockIdx.x * blockDim.x + threadIdx.x;
    if (i < n) p[i] = 0;
}

__global__ void count_edges_k(const int* __restrict__ dst, const int* __restrict__ et,
                              int* __restrict__ cnt) {
    int e = blockIdx.x * blockDim.x + threadIdx.x;
    if (e < NE) atomicAdd(&cnt[dst[e] * NR + et[e]], 1);
}

// ---- two-level exclusive scan over cnt[NSEG] -> rowstart[NSEG+1], cursor[NSEG] ----
__global__ void scanA_k(const int* __restrict__ cnt, int* __restrict__ incl,
                        int* __restrict__ blocksum) {
    __shared__ int s[SB];
    int t = threadIdx.x, i = blockIdx.x * SB + t;
    s[t] = (i < NSEG) ? cnt[i] : 0;
    __syncthreads();
    for (int off = 1; off < SB; off <<= 1) {
        int u = (t >= off) ? s[t - off] : 0;
        __syncthreads();
        s[t] += u;
        __syncthreads();
    }
    if (i < NSEG) incl[i] = s[t];
    if (t == SB - 1) blocksum[blockIdx.x] = s[t];
}

__global__ void scanB_k(const int* __restrict__ blocksum, int* __restrict__ blockoff) {
    __shared__ int s[1024];
    int t = threadIdx.x;
    s[t] = (t < SNB) ? blocksum[t] : 0;
    __syncthreads();
    for (int off = 1; off < 1024; off <<= 1) {
        int u = (t >= off) ? s[t - off] : 0;
        __syncthreads();
        s[t] += u;
        __syncthreads();
    }
    if (t < SNB) blockoff[t] = s[t];   // inclusive block sums
}

__global__ void scanC_k(const int* __restrict__ incl, const int* __restrict__ blockoff,
                        int* __restrict__ rowstart, int* __restrict__ cursor) {
    int i = blockIdx.x * blockDim.x + threadIdx.x;
    if (i >= NSEG) return;
    int b = i / SB;
    int Ri = incl[i] + (b > 0 ? blockoff[b - 1] : 0);
    rowstart[i + 1] = Ri;
    int prev;
    if (i == 0) { prev = 0; rowstart[0] = 0; }
    else {
        int b2 = (i - 1) / SB;
        prev = incl[i - 1] + (b2 > 0 ? blockoff[b2 - 1] : 0);
    }
    cursor[i] = prev;
}

// bucket edges by segment (dst*NR+rel); payload = src only
__global__ void build_pay_k(const int* __restrict__ srcs, const int* __restrict__ dsts,
                            const int* __restrict__ et, int* __restrict__ cursor,
                            int* __restrict__ pay) {
    int e = blockIdx.x * blockDim.x + threadIdx.x;
    if (e >= NE) return;
    int seg = dsts[e] * NR + et[e];
    int pos = atomicAdd(&cursor[seg], 1);
    pay[pos] = srcs[e];
}

// phase 1: agg[seg][o] = (1/c) * sum_{k in seg} x[pay[k]][o]; one wave per node
__global__ __launch_bounds__(256) void agg_mean_k(const float* __restrict__ x,
                                                  const int* __restrict__ rowstart,
                                                  const int* __restrict__ pay,
                                                  float* __restrict__ agg) {
    int n = (blockIdx.x * blockDim.x + threadIdx.x) >> 6;
    int o = threadIdx.x & 63;
    if (n >= NN) return;
    int base = n * NR;
    int k1next = rowstart[base];
    for (int r = 0; r < NR; ++r) {
        int k0 = k1next;
        int k1 = rowstart[base + r + 1];
        k1next = k1;
        float acc0 = 0.0f, acc1 = 0.0f;
        int k = k0;
        // 4-wide: batch pay loads, then 4 independent x-row loads in flight
        for (; k + 3 < k1; k += 4) {
            int s0 = pay[k], s1 = pay[k + 1], s2 = pay[k + 2], s3 = pay[k + 3];
            float v0 = x[s0 * D + o];
            float v1 = x[s1 * D + o];
            float v2 = x[s2 * D + o];
            float v3 = x[s3 * D + o];
            acc0 += v0 + v2;
            acc1 += v1 + v3;
        }
        for (; k < k1; ++k) acc0 += x[pay[k] * D + o];
        int c = k1 - k0;
        float nrm = (c > 0) ? 1.0f / (float)c : 0.0f;
        agg[(size_t)(base + r) * D + o] = (acc0 + acc1) * nrm;
    }
}

// phase 2: out[n,o] = bias[o] + sum_d x[n,d]*root[d,o] + sum_r sum_d agg[n,r,d]*W[r,d,o]
// wave owns CH nodes; W_r column (lane o) held in 64 VGPRs, reloaded per r
__global__ __launch_bounds__(256) void mix_k(const float* __restrict__ agg,
                                             const float* __restrict__ x,
                                             const float* __restrict__ W,
                                             const float* __restrict__ root,
                                             const float* __restrict__ bias,
                                             float* __restrict__ out) {
    int wid = (blockIdx.x * blockDim.x + threadIdx.x) >> 6;
    int o = threadIdx.x & 63;
    int n0 = wid * CH;
    if (n0 >= NN) return;
    float acc[CH];
#pragma unroll
    for (int c = 0; c < CH; ++c) acc[c] = 0.0f;
    float wcol[D];
    for (int r = 0; r < NR; ++r) {
        const float* Wr = W + r * D * D;
#pragma unroll
        for (int d = 0; d < D; ++d) wcol[d] = Wr[d * D + o];
#pragma unroll
        for (int c = 0; c < CH; ++c) {
            const float4* arow = (const float4*)(agg + ((size_t)(n0 + c) * NR + r) * D);
#pragma unroll
            for (int q = 0; q < D / 4; ++q) {
                float4 a = arow[q];
                acc[c] = fmaf(a.x, wcol[4 * q + 0], acc[c]);
                acc[c] = fmaf(a.y, wcol[4 * q + 1], acc[c]);
                acc[c] = fmaf(a.z, wcol[4 * q + 2], acc[c]);
                acc[c] = fmaf(a.w, wcol[4 * q + 3], acc[c]);
            }
        }
    }
    // root term
#pragma unroll
    for (int d = 0; d < D; ++d) wcol[d] = root[d * D + o];
#pragma unroll
    for (int c = 0; c < CH; ++c) {
        const float4* xrow = (const float4*)(x + (size_t)(n0 + c) * D);
#pragma unroll
        for (int q = 0; q < D / 4; ++q) {
            float4 a = xrow[q];
            acc[c] = fmaf(a.x, wcol[4 * q + 0], acc[c]);
            acc[c] = fmaf(a.y, wcol[4 * q + 1], acc[c]);
            acc[c] = fmaf(a.z, wcol[4 * q + 2], acc[c]);
            acc[c] = fmaf(a.w, wcol[4 * q + 3], acc[c]);
        }
    }
    float b = bias[o];
#pragma unroll
    for (int c = 0; c < CH; ++c) out[(size_t)(n0 + c) * D + o] = acc[c] + b;
}

// ---------- fallback path (small ws) ----------
__global__ void make_norm_k(const int* __restrict__ cnt, float* __restrict__ norm, int n) {
    int i = blockIdx.x * blockDim.x + threadIdx.x;
    if (i < n) {
        int c = cnt[i];
        norm[i] = (c > 0) ? 1.0f / (float)c : 0.0f;
    }
}

__global__ void init_out_k(const float* __restrict__ x, const float* __restrict__ root,
                           const float* __restrict__ bias, float* __restrict__ out) {
    int t = blockIdx.x * blockDim.x + threadIdx.x;
    int n = t >> 6;
    int o = t & 63;
    if (n >= NN) return;
    const float* xrow = x + n * D;
    float acc = bias[o];
#pragma unroll
    for (int d = 0; d < D; ++d) acc = fmaf(xrow[d], root[d * D + o], acc);
    out[t] = acc;
}

__global__ void scatter_mv_k(const int* __restrict__ srcs, const int* __restrict__ dsts,
                             const int* __restrict__ et, const float* __restrict__ x,
                             const float* __restrict__ W, const float* __restrict__ norm,
                             float* __restrict__ out) {
    int t = blockIdx.x * blockDim.x + threadIdx.x;
    int e = t >> 6;
    int o = t & 63;
    if (e >= NE) return;
    int s = srcs[e];
    int d2 = dsts[e];
    int r = et[e];
    float nrm = norm[d2 * NR + r];
    const float* xrow = x + s * D;
    const float* Wr = W + r * D * D + o;
    float acc = 0.0f;
#pragma unroll
    for (int d = 0; d < D; ++d) acc = fmaf(xrow[d], Wr[d * D], acc);
    atomicAdd(&out[d2 * D + o], acc * nrm);
}

extern "C" void kernel_launch(void* const* d_in, const int* in_sizes, int n_in,
                              void* d_out, int out_size, void* d_ws, size_t ws_size,
                              hipStream_t stream) {
    const float* x    = (const float*)d_in[0];
    const float* W    = (const float*)d_in[1];
    const float* root = (const float*)d_in[2];
    const float* bias = (const float*)d_in[3];
    const int*   ei   = (const int*)d_in[4];
    const int*   et   = (const int*)d_in[5];
    float* out = (float*)d_out;
    const int* srcs = ei;
    const int* dsts = ei + NE;

    char* ws = (char*)d_ws;
    size_t off = 0;
    int* cnt      = (int*)(ws + off); off += (size_t)NSEG * 4;
    int* incl     = (int*)(ws + off); off += (size_t)NSEG * 4;
    int* blocksum = (int*)(ws + off); off += (size_t)SNB * 4;
    int* blockoff = (int*)(ws + off); off += (size_t)SNB * 4;
    int* rowstart = (int*)(ws + off); off += (size_t)(NSEG + 1) * 4;
    int* cursor   = (int*)(ws + off); off += (size_t)NSEG * 4;
    int* pay      = (int*)(ws + off); off += (size_t)NE * 4;
    off = (off + 15) & ~(size_t)15;
    float* agg    = (float*)(ws + off); off += (size_t)NSEG * D * 4;  // 76.8 MB
    bool big = ws_size >= off;

    zero_i32_k<<<(NSEG + 255) / 256, 256, 0, stream>>>(cnt, NSEG);
    count_edges_k<<<(NE + 255) / 256, 256, 0, stream>>>(dsts, et, cnt);

    if (big) {
        scanA_k<<<SNB, SB, 0, stream>>>(cnt, incl, blocksum);
        scanB_k<<<1, 1024, 0, stream>>>(blocksum, blockoff);
        scanC_k<<<(NSEG + 255) / 256, 256, 0, stream>>>(incl, blockoff, rowstart, cursor);
        build_pay_k<<<(NE + 255) / 256, 256, 0, stream>>>(srcs, dsts, et, cursor, pay);
        agg_mean_k<<<((size_t)NN * 64 + 255) / 256, 256, 0, stream>>>(x, rowstart, pay, agg);
        int mix_waves = NN / CH;                       // 3125
        mix_k<<<((size_t)mix_waves * 64 + 255) / 256, 256, 0, stream>>>(agg, x, W, root, bias, out);
    } else {
        float* norm = (float*)incl;  // reuse
        make_norm_k<<<(NSEG + 255) / 256, 256, 0, stream>>>(cnt, norm, NSEG);
        init_out_k<<<((size_t)NN * 64 + 255) / 256, 256, 0, stream>>>(x, root, bias, out);
        scatter_mv_k<<<((size_t)NE * 64 + 255) / 256, 256, 0, stream>>>(srcs, dsts, et, x, W, norm, out);
    }
}

// Round 4
// 393.003 us; speedup vs baseline: 1.5323x; 1.5323x over previous
//
#include <hip/hip_runtime.h>

#define NN 50000
#define NE 1600000
#define D 64
#define NR 6
#define NSEG (NN * NR)          // 300000
#define KTOT 448                // 7 * 64  (6 relations + root slot)
#define SB 512
#define SNB ((NSEG + SB - 1) / SB)   // 586

__device__ __forceinline__ unsigned short f2bf(float f) {
    unsigned int u = __float_as_uint(f);
    unsigned int r = (u + 0x7FFF + ((u >> 16) & 1)) >> 16;   // RNE
    return (unsigned short)r;
}
__device__ __forceinline__ float bf2f(unsigned int h) {
    return __uint_as_float(h << 16);
}

__global__ void zero_i32_k(int* __restrict__ p, int n) {
    int i = blockIdx.x * blockDim.x + threadIdx.x;
    if (i < n) p[i] = 0;
}

__global__ void count_edges_k(const int* __restrict__ dst, const int* __restrict__ et,
                              int* __restrict__ cnt) {
    int e = blockIdx.x * blockDim.x + threadIdx.x;
    if (e < NE) atomicAdd(&cnt[dst[e] * NR + et[e]], 1);
}

// ---- two-level exclusive scan over cnt[NSEG] -> rowstart[NSEG+1], cursor[NSEG] ----
__global__ void scanA_k(const int* __restrict__ cnt, int* __restrict__ incl,
                        int* __restrict__ blocksum) {
    __shared__ int s[SB];
    int t = threadIdx.x, i = blockIdx.x * SB + t;
    s[t] = (i < NSEG) ? cnt[i] : 0;
    __syncthreads();
    for (int off = 1; off < SB; off <<= 1) {
        int u = (t >= off) ? s[t - off] : 0;
        __syncthreads();
        s[t] += u;
        __syncthreads();
    }
    if (i < NSEG) incl[i] = s[t];
    if (t == SB - 1) blocksum[blockIdx.x] = s[t];
}

__global__ void scanB_k(const int* __restrict__ blocksum, int* __restrict__ blockoff) {
    __shared__ int s[1024];
    int t = threadIdx.x;
    s[t] = (t < SNB) ? blocksum[t] : 0;
    __syncthreads();
    for (int off = 1; off < 1024; off <<= 1) {
        int u = (t >= off) ? s[t - off] : 0;
        __syncthreads();
        s[t] += u;
        __syncthreads();
    }
    if (t < SNB) blockoff[t] = s[t];
}

__global__ void scanC_k(const int* __restrict__ incl, const int* __restrict__ blockoff,
                        int* __restrict__ rowstart, int* __restrict__ cursor) {
    int i = blockIdx.x * blockDim.x + threadIdx.x;
    if (i >= NSEG) return;
    int b = i / SB;
    int Ri = incl[i] + (b > 0 ? blockoff[b - 1] : 0);
    rowstart[i + 1] = Ri;
    int prev;
    if (i == 0) { prev = 0; rowstart[0] = 0; }
    else {
        int b2 = (i - 1) / SB;
        prev = incl[i - 1] + (b2 > 0 ? blockoff[b2 - 1] : 0);
    }
    cursor[i] = prev;
}

__global__ void build_pay_k(const int* __restrict__ srcs, const int* __restrict__ dsts,
                            const int* __restrict__ et, int* __restrict__ cursor,
                            int* __restrict__ pay) {
    int e = blockIdx.x * blockDim.x + threadIdx.x;
    if (e >= NE) return;
    int seg = dsts[e] * NR + et[e];
    int pos = atomicAdd(&cursor[seg], 1);
    pay[pos] = srcs[e];
}

// A[n][KTOT] bf16: slots r=0..5 = per-relation means, slot 6 = x row.
__global__ __launch_bounds__(256) void agg_mean_k(const float* __restrict__ x,
                                                  const int* __restrict__ rowstart,
                                                  const int* __restrict__ pay,
                                                  unsigned short* __restrict__ A) {
    int n = (blockIdx.x * blockDim.x + threadIdx.x) >> 6;
    int o = threadIdx.x & 63;
    if (n >= NN) return;
    int base = n * NR;
    int k1n = rowstart[base];
    for (int r = 0; r < NR; ++r) {
        int k0 = k1n;
        int k1 = rowstart[base + r + 1];
        k1n = k1;
        float a0 = 0.0f, a1 = 0.0f;
        int k = k0;
        for (; k + 3 < k1; k += 4) {
            int s0 = pay[k], s1 = pay[k + 1], s2 = pay[k + 2], s3 = pay[k + 3];
            float v0 = x[s0 * D + o];
            float v1 = x[s1 * D + o];
            float v2 = x[s2 * D + o];
            float v3 = x[s3 * D + o];
            a0 += v0 + v2;
            a1 += v1 + v3;
        }
        for (; k < k1; ++k) a0 += x[pay[k] * D + o];
        int c = k1 - k0;
        float nrm = (c > 0) ? 1.0f / (float)c : 0.0f;
        A[(size_t)n * KTOT + r * 64 + o] = f2bf((a0 + a1) * nrm);
    }
    A[(size_t)n * KTOT + 6 * 64 + o] = f2bf(x[n * D + o]);
}

// BT[o][k] f32: k<384 -> W[k][o] (flat), else root[k-384][o]
__global__ void buildBT_k(const float* __restrict__ W, const float* __restrict__ root,
                          float* __restrict__ BT) {
    int idx = blockIdx.x * blockDim.x + threadIdx.x;
    if (idx >= 64 * KTOT) return;
    int o = idx / KTOT, k = idx - o * KTOT;
    BT[idx] = (k < 384) ? W[(size_t)k * 64 + o] : root[(size_t)(k - 384) * 64 + o];
}

// out[node][o] = bias[o] + sum_k A[node][k] * BT[o][k]
// block = 64 nodes (lane = node); wave w owns output channels 16w..16w+15.
// A chunk staged in LDS with XOR swizzle; BT via wave-uniform (scalar) loads.
__global__ __launch_bounds__(256) void mix2_k(const unsigned short* __restrict__ A,
                                              const float* __restrict__ BT,
                                              const float* __restrict__ bias,
                                              float* __restrict__ out) {
    __shared__ unsigned short Atile[64 * 64];   // 8 KB bf16, 128B per row, swizzled
    int t = threadIdx.x;
    int lane = t & 63;
    int w = t >> 6;
    int ob = __builtin_amdgcn_readfirstlane(w * 16);   // SGPR output-channel base
    int node0 = blockIdx.x * 64;
    int node = node0 + lane;

    float acc[16];
#pragma unroll
    for (int i = 0; i < 16; ++i) acc[i] = bias[ob + i];

    char* lds = (char*)Atile;
    for (int c = 0; c < 7; ++c) {
        __syncthreads();   // prior chunk's LDS reads complete everywhere
        // stage: 2 iters x 256 threads; row r, 16B chunk (t&7) of its 128B row
#pragma unroll
        for (int it = 0; it < 2; ++it) {
            int r = it * 32 + (t >> 3);
            int b16 = (t & 7) * 16;
            int row = node0 + r; if (row >= NN) row = NN - 1;
            const unsigned short* gp = A + (size_t)row * KTOT + c * 64 + (b16 >> 1);
            uint4 v = *(const uint4*)gp;                       // 8 bf16, coalesced
            int sb = b16 ^ ((r & 7) << 4);                     // T2 swizzle
            *(uint4*)(lds + r * 128 + sb) = v;
        }
        __syncthreads();
        // read own row -> a[64] f32 (conflict-free via same swizzle)
        float a[64];
#pragma unroll
        for (int k8 = 0; k8 < 8; ++k8) {
            int sb = (k8 * 16) ^ ((lane & 7) << 4);
            uint4 v = *(const uint4*)(lds + lane * 128 + sb);
            a[k8 * 8 + 0] = bf2f(v.x & 0xFFFFu);
            a[k8 * 8 + 1] = bf2f(v.x >> 16);
            a[k8 * 8 + 2] = bf2f(v.y & 0xFFFFu);
            a[k8 * 8 + 3] = bf2f(v.y >> 16);
            a[k8 * 8 + 4] = bf2f(v.z & 0xFFFFu);
            a[k8 * 8 + 5] = bf2f(v.z >> 16);
            a[k8 * 8 + 6] = bf2f(v.w & 0xFFFFu);
            a[k8 * 8 + 7] = bf2f(v.w >> 16);
        }
        // acc[ol] += a . BT[ob+ol][c*64 ..]  (BT addr wave-uniform -> s_load)
#pragma unroll
        for (int ol = 0; ol < 16; ++ol) {
            const float* bp = BT + (size_t)(ob + ol) * KTOT + c * 64;
#pragma unroll
            for (int kk = 0; kk < 64; ++kk)
                acc[ol] = fmaf(a[kk], bp[kk], acc[ol]);
        }
    }
    if (node < NN) {
#pragma unroll
        for (int q = 0; q < 4; ++q) {
            float4 v4 = make_float4(acc[4 * q], acc[4 * q + 1], acc[4 * q + 2], acc[4 * q + 3]);
            *(float4*)(out + (size_t)node * D + ob + 4 * q) = v4;
        }
    }
}

// ---------- fallback path (small ws) ----------
__global__ void make_norm_k(const int* __restrict__ cnt, float* __restrict__ norm, int n) {
    int i = blockIdx.x * blockDim.x + threadIdx.x;
    if (i < n) {
        int c = cnt[i];
        norm[i] = (c > 0) ? 1.0f / (float)c : 0.0f;
    }
}

__global__ void init_out_k(const float* __restrict__ x, const float* __restrict__ root,
                           const float* __restrict__ bias, float* __restrict__ out) {
    int t = blockIdx.x * blockDim.x + threadIdx.x;
    int n = t >> 6;
    int o = t & 63;
    if (n >= NN) return;
    const float* xrow = x + n * D;
    float acc = bias[o];
#pragma unroll
    for (int d = 0; d < D; ++d) acc = fmaf(xrow[d], root[d * D + o], acc);
    out[t] = acc;
}

__global__ void scatter_mv_k(const int* __restrict__ srcs, const int* __restrict__ dsts,
                             const int* __restrict__ et, const float* __restrict__ x,
                             const float* __restrict__ W, const float* __restrict__ norm,
                             float* __restrict__ out) {
    int t = blockIdx.x * blockDim.x + threadIdx.x;
    int e = t >> 6;
    int o = t & 63;
    if (e >= NE) return;
    int s = srcs[e];
    int d2 = dsts[e];
    int r = et[e];
    float nrm = norm[d2 * NR + r];
    const float* xrow = x + s * D;
    const float* Wr = W + r * D * D + o;
    float acc = 0.0f;
#pragma unroll
    for (int d = 0; d < D; ++d) acc = fmaf(xrow[d], Wr[d * D], acc);
    atomicAdd(&out[d2 * D + o], acc * nrm);
}

extern "C" void kernel_launch(void* const* d_in, const int* in_sizes, int n_in,
                              void* d_out, int out_size, void* d_ws, size_t ws_size,
                              hipStream_t stream) {
    const float* x    = (const float*)d_in[0];
    const float* W    = (const float*)d_in[1];
    const float* root = (const float*)d_in[2];
    const float* bias = (const float*)d_in[3];
    const int*   ei   = (const int*)d_in[4];
    const int*   et   = (const int*)d_in[5];
    float* out = (float*)d_out;
    const int* srcs = ei;
    const int* dsts = ei + NE;

    // persistent region
    char* ws = (char*)d_ws;
    size_t off = 0;
    int*   rowstart = (int*)(ws + off); off += (size_t)(NSEG + 1) * 4;
    int*   pay      = (int*)(ws + off); off += (size_t)NE * 4;
    off = (off + 255) & ~(size_t)255;
    float* BT       = (float*)(ws + off); off += (size_t)64 * KTOT * 4;
    off = (off + 255) & ~(size_t)255;
    unsigned short* A = (unsigned short*)(ws + off);
    size_t a_bytes = (size_t)NN * KTOT * 2;          // 44.8 MB
    size_t need = off + a_bytes;
    // scan temporaries overlap A's region (dead before agg_mean writes A)
    char* tmp = (char*)A;
    int* cnt      = (int*)tmp;                         tmp += (size_t)NSEG * 4;
    int* incl     = (int*)tmp;                         tmp += (size_t)NSEG * 4;
    int* blocksum = (int*)tmp;                         tmp += (size_t)SNB * 4;
    int* blockoff = (int*)tmp;                         tmp += (size_t)SNB * 4;
    int* cursor   = (int*)tmp;                         tmp += (size_t)NSEG * 4;
    bool big = (ws_size >= need) && ((size_t)(tmp - (char*)A) <= a_bytes);

    if (big) {
        zero_i32_k<<<(NSEG + 255) / 256, 256, 0, stream>>>(cnt, NSEG);
        count_edges_k<<<(NE + 255) / 256, 256, 0, stream>>>(dsts, et, cnt);
        scanA_k<<<SNB, SB, 0, stream>>>(cnt, incl, blocksum);
        scanB_k<<<1, 1024, 0, stream>>>(blocksum, blockoff);
        scanC_k<<<(NSEG + 255) / 256, 256, 0, stream>>>(incl, blockoff, rowstart, cursor);
        build_pay_k<<<(NE + 255) / 256, 256, 0, stream>>>(srcs, dsts, et, cursor, pay);
        buildBT_k<<<(64 * KTOT + 255) / 256, 256, 0, stream>>>(W, root, BT);
        agg_mean_k<<<((size_t)NN * 64 + 255) / 256, 256, 0, stream>>>(x, rowstart, pay, A);
        mix2_k<<<(NN + 63) / 64, 256, 0, stream>>>(A, BT, bias, out);
    } else {
        int* cnt2  = (int*)(ws);
        float* norm = (float*)(ws + (size_t)NSEG * 4);
        zero_i32_k<<<(NSEG + 255) / 256, 256, 0, stream>>>(cnt2, NSEG);
        count_edges_k<<<(NE + 255) / 256, 256, 0, stream>>>(dsts, et, cnt2);
        make_norm_k<<<(NSEG + 255) / 256, 256, 0, stream>>>(cnt2, norm, NSEG);
        init_out_k<<<((size_t)NN * 64 + 255) / 256, 256, 0, stream>>>(x, root, bias, out);
        scatter_mv_k<<<((size_t)NE * 64 + 255) / 256, 256, 0, stream>>>(srcs, dsts, et, x, W, norm, out);
    }
}

// Round 5
// 350.185 us; speedup vs baseline: 1.7196x; 1.1223x over previous
//
#include <hip/hip_runtime.h>

#define NN 50000
#define NE 1600000
#define D 64
#define NR 6
#define NSEG (NN * NR)          // 300000
#define KTOT 448                // 7 * 64  (6 relations + root slot)
#define SB 512
#define SNB ((NSEG + SB - 1) / SB)   // 586

typedef __attribute__((ext_vector_type(8))) short short8;
typedef __attribute__((ext_vector_type(4))) float f32x4;

__device__ __forceinline__ unsigned short f2bf(float f) {
    unsigned int u = __float_as_uint(f);
    unsigned int r = (u + 0x7FFF + ((u >> 16) & 1)) >> 16;   // RNE
    return (unsigned short)r;
}

__global__ void zero_i32_k(int* __restrict__ p, int n) {
    int i = blockIdx.x * blockDim.x + threadIdx.x;
    if (i < n) p[i] = 0;
}

__global__ void count_edges_k(const int* __restrict__ dst, const int* __restrict__ et,
                              int* __restrict__ cnt) {
    int e = blockIdx.x * blockDim.x + threadIdx.x;
    if (e < NE) atomicAdd(&cnt[dst[e] * NR + et[e]], 1);
}

// ---- two-level exclusive scan over cnt[NSEG] -> rowstart[NSEG+1], cursor[NSEG] ----
__global__ void scanA_k(const int* __restrict__ cnt, int* __restrict__ incl,
                        int* __restrict__ blocksum) {
    __shared__ int s[SB];
    int t = threadIdx.x, i = blockIdx.x * SB + t;
    s[t] = (i < NSEG) ? cnt[i] : 0;
    __syncthreads();
    for (int off = 1; off < SB; off <<= 1) {
        int u = (t >= off) ? s[t - off] : 0;
        __syncthreads();
        s[t] += u;
        __syncthreads();
    }
    if (i < NSEG) incl[i] = s[t];
    if (t == SB - 1) blocksum[blockIdx.x] = s[t];
}

__global__ void scanB_k(const int* __restrict__ blocksum, int* __restrict__ blockoff) {
    __shared__ int s[1024];
    int t = threadIdx.x;
    s[t] = (t < SNB) ? blocksum[t] : 0;
    __syncthreads();
    for (int off = 1; off < 1024; off <<= 1) {
        int u = (t >= off) ? s[t - off] : 0;
        __syncthreads();
        s[t] += u;
        __syncthreads();
    }
    if (t < SNB) blockoff[t] = s[t];
}

__global__ void scanC_k(const int* __restrict__ incl, const int* __restrict__ blockoff,
                        int* __restrict__ rowstart, int* __restrict__ cursor) {
    int i = blockIdx.x * blockDim.x + threadIdx.x;
    if (i >= NSEG) return;
    int b = i / SB;
    int Ri = incl[i] + (b > 0 ? blockoff[b - 1] : 0);
    rowstart[i + 1] = Ri;
    int prev;
    if (i == 0) { prev = 0; rowstart[0] = 0; }
    else {
        int b2 = (i - 1) / SB;
        prev = incl[i - 1] + (b2 > 0 ? blockoff[b2 - 1] : 0);
    }
    cursor[i] = prev;
}

__global__ void build_pay_k(const int* __restrict__ srcs, const int* __restrict__ dsts,
                            const int* __restrict__ et, int* __restrict__ cursor,
                            int* __restrict__ pay) {
    int e = blockIdx.x * blockDim.x + threadIdx.x;
    if (e >= NE) return;
    int seg = dsts[e] * NR + et[e];
    int pos = atomicAdd(&cursor[seg], 1);
    pay[pos] = srcs[e];
}

// one wave per segment (wid < NSEG): A[n][r*64+o] = mean of x[src][o] over segment.
// wid in [NSEG, NSEG+NN): copy x row into slot 6.
__global__ __launch_bounds__(256) void agg2_k(const float* __restrict__ x,
                                              const int* __restrict__ rowstart,
                                              const int* __restrict__ pay,
                                              unsigned short* __restrict__ A) {
    int wid = (blockIdx.x * blockDim.x + threadIdx.x) >> 6;
    int o = threadIdx.x & 63;
    if (wid < NSEG) {
        int n = wid / NR;
        int r = wid - n * NR;
        int k0 = rowstart[wid], k1 = rowstart[wid + 1];
        float a0 = 0.f, a1 = 0.f, a2 = 0.f, a3 = 0.f;
        int k = k0;
        for (; k + 7 < k1; k += 8) {
            int s0 = pay[k],     s1 = pay[k + 1], s2 = pay[k + 2], s3 = pay[k + 3];
            int s4 = pay[k + 4], s5 = pay[k + 5], s6 = pay[k + 6], s7 = pay[k + 7];
            float v0 = x[s0 * D + o], v1 = x[s1 * D + o], v2 = x[s2 * D + o], v3 = x[s3 * D + o];
            float v4 = x[s4 * D + o], v5 = x[s5 * D + o], v6 = x[s6 * D + o], v7 = x[s7 * D + o];
            a0 += v0 + v4; a1 += v1 + v5; a2 += v2 + v6; a3 += v3 + v7;
        }
        for (; k < k1; ++k) a0 += x[pay[k] * D + o];
        int c = k1 - k0;
        float nrm = (c > 0) ? 1.0f / (float)c : 0.0f;
        A[(size_t)n * KTOT + r * 64 + o] = f2bf((a0 + a1 + a2 + a3) * nrm);
    } else if (wid < NSEG + NN) {
        int n = wid - NSEG;
        A[(size_t)n * KTOT + 6 * 64 + o] = f2bf(x[n * D + o]);
    }
}

// Bfrag[((nt*14 + ks)*64 + lane)*8 + j] = bf16( B[ks*32 + (lane>>4)*8 + j][nt*16 + (lane&15)] )
// where B[k][n] = k<384 ? W[k][n] : root[k-384][n]
__global__ void buildBfrag_k(const float* __restrict__ W, const float* __restrict__ root,
                             unsigned short* __restrict__ Bfrag) {
    int t = blockIdx.x * blockDim.x + threadIdx.x;
    if (t >= 4 * 14 * 64 * 8) return;
    int j = t & 7;
    int lane = (t >> 3) & 63;
    int rest = t >> 9;
    int ks = rest % 14;
    int nt = rest / 14;
    int k = ks * 32 + ((lane >> 4) * 8) + j;
    int n = nt * 16 + (lane & 15);
    float v = (k < 384) ? W[(size_t)k * 64 + n] : root[(size_t)(k - 384) * 64 + n];
    Bfrag[t] = f2bf(v);
}

// MFMA GEMM: out[m][n] = bias[n] + sum_k A[m][k]*B[k][n]; M=NN, K=448, N=64.
// Block = 4 waves, each wave a 16-row strip x 64 cols. No LDS, no barriers.
__global__ __launch_bounds__(256) void mix3_k(const unsigned short* __restrict__ A,
                                              const unsigned short* __restrict__ Bfrag,
                                              const float* __restrict__ bias,
                                              float* __restrict__ out) {
    int t = threadIdx.x;
    int lane = t & 63;
    int w = t >> 6;
    int rowb = blockIdx.x * 64 + w * 16;
    int arow = rowb + (lane & 15);
    if (arow >= NN) arow = NN - 1;
    const short8* ap = (const short8*)(A + (size_t)arow * KTOT + ((lane >> 4) * 8));
    const short8* bp = (const short8*)Bfrag + lane;
    f32x4 acc0 = {0.f, 0.f, 0.f, 0.f};
    f32x4 acc1 = acc0, acc2 = acc0, acc3 = acc0;
#pragma unroll
    for (int ks = 0; ks < 14; ++ks) {
        short8 a = ap[ks * 4];                       // advance 32 elems per ks
        short8 b0 = bp[(0 * 14 + ks) * 64];
        short8 b1 = bp[(1 * 14 + ks) * 64];
        short8 b2 = bp[(2 * 14 + ks) * 64];
        short8 b3 = bp[(3 * 14 + ks) * 64];
        acc0 = __builtin_amdgcn_mfma_f32_16x16x32_bf16(a, b0, acc0, 0, 0, 0);
        acc1 = __builtin_amdgcn_mfma_f32_16x16x32_bf16(a, b1, acc1, 0, 0, 0);
        acc2 = __builtin_amdgcn_mfma_f32_16x16x32_bf16(a, b2, acc2, 0, 0, 0);
        acc3 = __builtin_amdgcn_mfma_f32_16x16x32_bf16(a, b3, acc3, 0, 0, 0);
    }
    int col = lane & 15;
    int rout = rowb + (lane >> 4) * 4;
    float bv0 = bias[0 * 16 + col];
    float bv1 = bias[1 * 16 + col];
    float bv2 = bias[2 * 16 + col];
    float bv3 = bias[3 * 16 + col];
#pragma unroll
    for (int j = 0; j < 4; ++j) {
        int rr = rout + j;
        if (rr < NN) {
            float* op = out + (size_t)rr * 64;
            op[0 * 16 + col] = acc0[j] + bv0;
            op[1 * 16 + col] = acc1[j] + bv1;
            op[2 * 16 + col] = acc2[j] + bv2;
            op[3 * 16 + col] = acc3[j] + bv3;
        }
    }
}

// ---------- fallback path (small ws) ----------
__global__ void make_norm_k(const int* __restrict__ cnt, float* __restrict__ norm, int n) {
    int i = blockIdx.x * blockDim.x + threadIdx.x;
    if (i < n) {
        int c = cnt[i];
        norm[i] = (c > 0) ? 1.0f / (float)c : 0.0f;
    }
}

__global__ void init_out_k(const float* __restrict__ x, const float* __restrict__ root,
                           const float* __restrict__ bias, float* __restrict__ out) {
    int t = blockIdx.x * blockDim.x + threadIdx.x;
    int n = t >> 6;
    int o = t & 63;
    if (n >= NN) return;
    const float* xrow = x + n * D;
    float acc = bias[o];
#pragma unroll
    for (int d = 0; d < D; ++d) acc = fmaf(xrow[d], root[d * D + o], acc);
    out[t] = acc;
}

__global__ void scatter_mv_k(const int* __restrict__ srcs, const int* __restrict__ dsts,
                             const int* __restrict__ et, const float* __restrict__ x,
                             const float* __restrict__ W, const float* __restrict__ norm,
                             float* __restrict__ out) {
    int t = blockIdx.x * blockDim.x + threadIdx.x;
    int e = t >> 6;
    int o = t & 63;
    if (e >= NE) return;
    int s = srcs[e];
    int d2 = dsts[e];
    int r = et[e];
    float nrm = norm[d2 * NR + r];
    const float* xrow = x + s * D;
    const float* Wr = W + r * D * D + o;
    float acc = 0.0f;
#pragma unroll
    for (int d = 0; d < D; ++d) acc = fmaf(xrow[d], Wr[d * D], acc);
    atomicAdd(&out[d2 * D + o], acc * nrm);
}

extern "C" void kernel_launch(void* const* d_in, const int* in_sizes, int n_in,
                              void* d_out, int out_size, void* d_ws, size_t ws_size,
                              hipStream_t stream) {
    const float* x    = (const float*)d_in[0];
    const float* W    = (const float*)d_in[1];
    const float* root = (const float*)d_in[2];
    const float* bias = (const float*)d_in[3];
    const int*   ei   = (const int*)d_in[4];
    const int*   et   = (const int*)d_in[5];
    float* out = (float*)d_out;
    const int* srcs = ei;
    const int* dsts = ei + NE;

    // persistent region
    char* ws = (char*)d_ws;
    size_t off = 0;
    int*   rowstart = (int*)(ws + off); off += (size_t)(NSEG + 1) * 4;
    int*   pay      = (int*)(ws + off); off += (size_t)NE * 4;
    off = (off + 255) & ~(size_t)255;
    unsigned short* Bfrag = (unsigned short*)(ws + off); off += (size_t)4 * 14 * 64 * 8 * 2;
    off = (off + 255) & ~(size_t)255;
    unsigned short* A = (unsigned short*)(ws + off);
    size_t a_bytes = (size_t)NN * KTOT * 2;          // 44.8 MB
    size_t need = off + a_bytes;
    // scan temporaries overlap A's region (dead before agg2 writes A)
    char* tmp = (char*)A;
    int* cnt      = (int*)tmp;                         tmp += (size_t)NSEG * 4;
    int* incl     = (int*)tmp;                         tmp += (size_t)NSEG * 4;
    int* blocksum = (int*)tmp;                         tmp += (size_t)SNB * 4;
    int* blockoff = (int*)tmp;                         tmp += (size_t)SNB * 4;
    int* cursor   = (int*)tmp;                         tmp += (size_t)NSEG * 4;
    bool big = (ws_size >= need) && ((size_t)(tmp - (char*)A) <= a_bytes);

    if (big) {
        zero_i32_k<<<(NSEG + 255) / 256, 256, 0, stream>>>(cnt, NSEG);
        count_edges_k<<<(NE + 255) / 256, 256, 0, stream>>>(dsts, et, cnt);
        scanA_k<<<SNB, SB, 0, stream>>>(cnt, incl, blocksum);
        scanB_k<<<1, 1024, 0, stream>>>(blocksum, blockoff);
        scanC_k<<<(NSEG + 255) / 256, 256, 0, stream>>>(incl, blockoff, rowstart, cursor);
        build_pay_k<<<(NE + 255) / 256, 256, 0, stream>>>(srcs, dsts, et, cursor, pay);
        buildBfrag_k<<<(4 * 14 * 64 * 8 + 255) / 256, 256, 0, stream>>>(W, root, Bfrag);
        int aggwaves = NSEG + NN;                     // 350000
        agg2_k<<<(aggwaves + 3) / 4, 256, 0, stream>>>(x, rowstart, pay, A);
        mix3_k<<<(NN + 63) / 64, 256, 0, stream>>>(A, Bfrag, bias, out);
    } else {
        int* cnt2  = (int*)(ws);
        float* norm = (float*)(ws + (size_t)NSEG * 4);
        zero_i32_k<<<(NSEG + 255) / 256, 256, 0, stream>>>(cnt2, NSEG);
        count_edges_k<<<(NE + 255) / 256, 256, 0, stream>>>(dsts, et, cnt2);
        make_norm_k<<<(NSEG + 255) / 256, 256, 0, stream>>>(cnt2, norm, NSEG);
        init_out_k<<<((size_t)NN * 64 + 255) / 256, 256, 0, stream>>>(x, root, bias, out);
        scatter_mv_k<<<((size_t)NE * 64 + 255) / 256, 256, 0, stream>>>(srcs, dsts, et, x, W, norm, out);
    }
}